// Round 1
// baseline (656.151 us; speedup 1.0000x reference)
//
#include <hip/hip_runtime.h>
#include <math.h>

// Attention_28200755265553: B=64,T=128,S=1024,IN=OUT=1024,CAT=2048
// Pipeline: RTZ hi/lo bf16 split (exact hi, lo=residual) for the score path
// (Ootomo 3-MFMA); v_perm packing makes every fp32->bf16 conversion ~1 op.
// All k-contiguous bf16 staging via global_load_lds width=16.
//
// R1 change: all four MFMA GEMMs moved from 4-wave (256t) to 8-wave (512t)
// blocks on the SAME 128x128 tiles. Grid stays 512 blocks -> 2 blocks/CU,
// but resident waves/CU double 8->16 (4/SIMD, __launch_bounds__(512,4)
// caps VGPR at 128: acc 32 + frags 48 fits). Theory: the 2-barrier g2lds
// structure is stall-dominated (m233) and 2 waves/SIMD gave half the
// cross-wave stall coverage of the m97 equilibrium (~12-16 waves/CU).
// Also: scores' Bh/Bl padded to stride 40 (2-way instead of 8-way bank
// conflict on ds_read_b128, same fix as gemm_ctx's BSTR).

typedef __attribute__((ext_vector_type(8))) short short8;
typedef __attribute__((ext_vector_type(4))) float f32x4;
typedef __attribute__((ext_vector_type(4))) unsigned short u16x4;

__device__ __forceinline__ unsigned int fbits(float x) {
    union { float f; unsigned int u; } v; v.f = x; return v.u;
}
__device__ __forceinline__ float asfloat(unsigned int u) {
    union { unsigned int u; float f; } v; v.u = u; return v.f;
}
// truncate to bf16-representable fp32 (RTZ): keep top 16 bits
__device__ __forceinline__ float truncbf(float x) { return asfloat(fbits(x) & 0xffff0000u); }
// pack two floats' top-16 bits: low ushort = bf16_rtz(X), high = bf16_rtz(Y). 1 v_perm.
__device__ __forceinline__ unsigned int pkhi(float X, float Y) {
    return __builtin_amdgcn_perm(fbits(Y), fbits(X), 0x07060302u);
}
// RNE fp32->bf16 (used only in cold paths)
__device__ __forceinline__ unsigned short f2bf(float x) {
    unsigned int u = fbits(x);
    u += 0x7fffu + ((u >> 16) & 1u);
    return (unsigned short)(u >> 16);
}
// async global->LDS, 16B per lane; lds ptr must be linear in tid
__device__ __forceinline__ void g2lds16(const void* g, void* l) {
    __builtin_amdgcn_global_load_lds(
        (const __attribute__((address_space(1))) void*)g,
        (__attribute__((address_space(3))) void*)l, 16, 0, 0);
}

// ---------------------------------------------------------------------------
// elementwise pre-passes
// ---------------------------------------------------------------------------
__global__ __launch_bounds__(256) void split_rtz(
    const float* __restrict__ src, unsigned short* __restrict__ hi,
    unsigned short* __restrict__ lo)
{
    long long i = (long long)blockIdx.x * 256 + threadIdx.x;
    float4 x = *(const float4*)(src + i * 4);
    uint2 h, l;
    h.x = pkhi(x.x, x.y); h.y = pkhi(x.z, x.w);
    float l0 = x.x - truncbf(x.x), l1 = x.y - truncbf(x.y);
    float l2 = x.z - truncbf(x.z), l3 = x.w - truncbf(x.w);
    l.x = pkhi(l0, l1); l.y = pkhi(l2, l3);
    *(uint2*)(hi + i * 4) = h;
    *(uint2*)(lo + i * 4) = l;
}

__global__ __launch_bounds__(256) void cvt_f32(
    const float* __restrict__ src, unsigned short* __restrict__ dst)
{
    long long i = (long long)blockIdx.x * 256 + threadIdx.x;
    float4 x = *(const float4*)(src + i * 4);
    u16x4 h; h[0] = f2bf(x.x); h[1] = f2bf(x.y); h[2] = f2bf(x.z); h[3] = f2bf(x.w);
    *(u16x4*)(dst + i * 4) = h;
}

// ---------------------------------------------------------------------------
// q_proj: C = dec @ W_attn^T, split-bf16 (3 MFMA), K=N=1024. Pure g2lds
// staging; output written as RTZ hi/lo bf16. grid (64,8,1), 512 threads.
// ---------------------------------------------------------------------------
__global__ __launch_bounds__(512, 4) void gemm3_qproj(
    const unsigned short* __restrict__ Ahi, const unsigned short* __restrict__ Alo,
    const unsigned short* __restrict__ Bhi, const unsigned short* __restrict__ Blo,
    unsigned short* __restrict__ Chi, unsigned short* __restrict__ Clo)
{
    const int m0 = blockIdx.x * 128, n0 = blockIdx.y * 128;
    __shared__ __align__(16) unsigned short Ah[128*32], Al[128*32], Bh[128*32], Bl[128*32];

    const int tid = threadIdx.x, lane = tid & 63, wave = tid >> 6;
    const int wm = (wave >> 2) * 64, wn = (wave & 3) * 32;   // 2M x 4N waves, 64x32 each
    const int fr = lane & 15, kq = lane >> 4;
    const int row0 = tid >> 2, c80 = (tid & 3) * 8;          // 512 threads: 1 g2lds per 8KB buf

    f32x4 zero = {0.f, 0.f, 0.f, 0.f};
    f32x4 acc[4][2];
    #pragma unroll
    for (int i = 0; i < 4; i++)
        #pragma unroll
        for (int j = 0; j < 2; j++) acc[i][j] = zero;

    for (int k0 = 0; k0 < 1024; k0 += 32) {
        const unsigned short* pa = Ahi + (long long)(m0 + row0) * 1024 + k0 + c80;
        const unsigned short* pl = Alo + (long long)(m0 + row0) * 1024 + k0 + c80;
        const unsigned short* pb = Bhi + (long long)(n0 + row0) * 1024 + k0 + c80;
        const unsigned short* pm = Blo + (long long)(n0 + row0) * 1024 + k0 + c80;
        g2lds16(pa, &Ah[tid*8]);
        g2lds16(pl, &Al[tid*8]);
        g2lds16(pb, &Bh[tid*8]);
        g2lds16(pm, &Bl[tid*8]);
        __syncthreads();

        short8 fah[4], fal[4], fbh[2], fbl[2];
        #pragma unroll
        for (int fi = 0; fi < 4; fi++) {
            fah[fi] = *(const short8*)&Ah[(wm + fi*16 + fr)*32 + kq*8];
            fal[fi] = *(const short8*)&Al[(wm + fi*16 + fr)*32 + kq*8];
        }
        #pragma unroll
        for (int fj = 0; fj < 2; fj++) {
            fbh[fj] = *(const short8*)&Bh[(wn + fj*16 + fr)*32 + kq*8];
            fbl[fj] = *(const short8*)&Bl[(wn + fj*16 + fr)*32 + kq*8];
        }
        #pragma unroll
        for (int fi = 0; fi < 4; fi++)
            #pragma unroll
            for (int fj = 0; fj < 2; fj++) {
                acc[fi][fj] = __builtin_amdgcn_mfma_f32_16x16x32_bf16(fah[fi], fbh[fj], acc[fi][fj], 0, 0, 0);
                acc[fi][fj] = __builtin_amdgcn_mfma_f32_16x16x32_bf16(fah[fi], fbl[fj], acc[fi][fj], 0, 0, 0);
                acc[fi][fj] = __builtin_amdgcn_mfma_f32_16x16x32_bf16(fal[fi], fbh[fj], acc[fi][fj], 0, 0, 0);
            }
        __syncthreads();
    }

    #pragma unroll
    for (int fi = 0; fi < 4; fi++) {
        int rb = m0 + wm + fi*16 + kq*4;
        #pragma unroll
        for (int fj = 0; fj < 2; fj++) {
            int col = n0 + wn + fj*16 + fr;
            #pragma unroll
            for (int j = 0; j < 4; j++) {
                float x = acc[fi][fj][j];
                unsigned int hb = fbits(x) & 0xffff0000u;
                Chi[(long long)(rb + j) * 1024 + col] = (unsigned short)(hb >> 16);
                float l = x - asfloat(hb);
                Clo[(long long)(rb + j) * 1024 + col] = (unsigned short)(fbits(l) >> 16);
            }
        }
    }
}

// ---------------------------------------------------------------------------
// scores: per batch C = q @ enc^T, split-bf16 (3 MFMA). A via g2lds from
// pre-split q; B (enc fp32) RTZ-split on the fly. B tiles padded (stride 40)
// to break the 8-way ds_read_b128 conflict. grid (1,8,64), 512 threads.
// ---------------------------------------------------------------------------
#define SSTR 40
__global__ __launch_bounds__(512, 4) void gemm3_scores(
    const unsigned short* __restrict__ Qhi, const unsigned short* __restrict__ Qlo,
    const float* __restrict__ enc, float* __restrict__ C)
{
    const int bz = blockIdx.z, n0 = blockIdx.y * 128;
    const unsigned short* Ahb = Qhi + (long long)bz * 128 * 1024;
    const unsigned short* Alb = Qlo + (long long)bz * 128 * 1024;
    const float* Bb = enc + (long long)bz * 1024 * 1024;
    float* Cb = C + (long long)bz * 128 * 1024;

    __shared__ __align__(16) unsigned short Ah[128*32], Al[128*32], Bh[128*SSTR], Bl[128*SSTR];

    const int tid = threadIdx.x, lane = tid & 63, wave = tid >> 6;
    const int wm = (wave >> 2) * 64, wn = (wave & 3) * 32;
    const int fr = lane & 15, kq = lane >> 4;
    const int row0 = tid >> 2, c80 = (tid & 3) * 8;

    f32x4 zero = {0.f, 0.f, 0.f, 0.f};
    f32x4 acc[4][2];
    #pragma unroll
    for (int i = 0; i < 4; i++)
        #pragma unroll
        for (int j = 0; j < 2; j++) acc[i][j] = zero;

    for (int k0 = 0; k0 < 1024; k0 += 32) {
        const unsigned short* pa = Ahb + (long long)row0 * 1024 + k0 + c80;
        const unsigned short* pl = Alb + (long long)row0 * 1024 + k0 + c80;
        g2lds16(pa, &Ah[tid*8]);
        g2lds16(pl, &Al[tid*8]);

        // B: 128(n) x 32(k) fp32 -> RTZ hi/lo bf16, padded rows
        #pragma unroll
        for (int i = 0; i < 2; i++) {
            int u = i * 512 + tid;
            int row = u >> 3, c4 = (u & 7) * 4;
            float4 b4 = *(const float4*)(Bb + (long long)(n0 + row) * 1024 + k0 + c4);
            uint2 hh, ll;
            hh.x = pkhi(b4.x, b4.y); hh.y = pkhi(b4.z, b4.w);
            float l0 = b4.x - truncbf(b4.x), l1 = b4.y - truncbf(b4.y);
            float l2 = b4.z - truncbf(b4.z), l3 = b4.w - truncbf(b4.w);
            ll.x = pkhi(l0, l1); ll.y = pkhi(l2, l3);
            *(uint2*)&Bh[row*SSTR + c4] = hh;
            *(uint2*)&Bl[row*SSTR + c4] = ll;
        }
        __syncthreads();

        short8 fah[4], fal[4], fbh[2], fbl[2];
        #pragma unroll
        for (int fi = 0; fi < 4; fi++) {
            fah[fi] = *(const short8*)&Ah[(wm + fi*16 + fr)*32 + kq*8];
            fal[fi] = *(const short8*)&Al[(wm + fi*16 + fr)*32 + kq*8];
        }
        #pragma unroll
        for (int fj = 0; fj < 2; fj++) {
            fbh[fj] = *(const short8*)&Bh[(wn + fj*16 + fr)*SSTR + kq*8];
            fbl[fj] = *(const short8*)&Bl[(wn + fj*16 + fr)*SSTR + kq*8];
        }
        #pragma unroll
        for (int fi = 0; fi < 4; fi++)
            #pragma unroll
            for (int fj = 0; fj < 2; fj++) {
                acc[fi][fj] = __builtin_amdgcn_mfma_f32_16x16x32_bf16(fah[fi], fbh[fj], acc[fi][fj], 0, 0, 0);
                acc[fi][fj] = __builtin_amdgcn_mfma_f32_16x16x32_bf16(fah[fi], fbl[fj], acc[fi][fj], 0, 0, 0);
                acc[fi][fj] = __builtin_amdgcn_mfma_f32_16x16x32_bf16(fal[fi], fbh[fj], acc[fi][fj], 0, 0, 0);
            }
        __syncthreads();
    }

    #pragma unroll
    for (int fi = 0; fi < 4; fi++) {
        int rb = wm + fi*16 + kq*4;
        #pragma unroll
        for (int fj = 0; fj < 2; fj++) {
            int col = n0 + wn + fj*16 + fr;
            #pragma unroll
            for (int j = 0; j < 4; j++)
                Cb[(long long)(rb + j) * 1024 + col] = acc[fi][fj][j];
        }
    }
}

// ---------------------------------------------------------------------------
// masked softmax over S=1024 (fp32 weights in d_out + bf16 copy for ctx GEMM)
// ---------------------------------------------------------------------------
__global__ __launch_bounds__(256) void softmax_mask(
    float* __restrict__ sw, const int* __restrict__ mask,
    unsigned short* __restrict__ wbf)
{
    const int row = blockIdx.x;          // b*128 + t
    const int b = row >> 7;
    const int tid = threadIdx.x, lane = tid & 63, wave = tid >> 6;
    float* sr = sw + (long long)row * 1024;
    const int* mr = mask + (long long)b * 1024;

    float4 x = *(const float4*)(sr + tid * 4);
    int4  mk = *(const int4*)(mr + tid * 4);
    float v0 = mk.x ? -INFINITY : x.x;
    float v1 = mk.y ? -INFINITY : x.y;
    float v2 = mk.z ? -INFINITY : x.z;
    float v3 = mk.w ? -INFINITY : x.w;

    float mx = fmaxf(fmaxf(v0, v1), fmaxf(v2, v3));
    #pragma unroll
    for (int off = 32; off; off >>= 1) mx = fmaxf(mx, __shfl_xor(mx, off));
    __shared__ float redm[4], reds[4];
    if (lane == 0) redm[wave] = mx;
    __syncthreads();
    mx = fmaxf(fmaxf(redm[0], redm[1]), fmaxf(redm[2], redm[3]));

    float p0 = __expf(v0 - mx), p1 = __expf(v1 - mx);
    float p2 = __expf(v2 - mx), p3 = __expf(v3 - mx);
    float s = (p0 + p1) + (p2 + p3);
    #pragma unroll
    for (int off = 32; off; off >>= 1) s += __shfl_xor(s, off);
    if (lane == 0) reds[wave] = s;
    __syncthreads();
    s = (reds[0] + reds[1]) + (reds[2] + reds[3]);
    float inv = 1.0f / s;

    float w0 = p0*inv, w1 = p1*inv, w2 = p2*inv, w3 = p3*inv;
    float4 w4; w4.x = w0; w4.y = w1; w4.z = w2; w4.w = w3;
    *(float4*)(sr + tid * 4) = w4;
    u16x4 wb; wb[0] = f2bf(w0); wb[1] = f2bf(w1); wb[2] = f2bf(w2); wb[3] = f2bf(w3);
    *(u16x4*)(wbf + (long long)row * 1024 + tid * 4) = wb;
}

// ---------------------------------------------------------------------------
// ctx = weights @ enc per batch. A (w_bf) via g2lds; B = enc fp32 transposed
// via 4x2 register blocks, RTZ+perm pack. grid (1,8,64), 512 threads.
// ---------------------------------------------------------------------------
#define BSTR 40
__global__ __launch_bounds__(512, 4) void gemm_ctx(
    const unsigned short* __restrict__ Wb, const float* __restrict__ enc,
    unsigned short* __restrict__ ctx)
{
    const int bz = blockIdx.z, n0 = blockIdx.y * 128;
    const unsigned short* Ab = Wb + (long long)bz * 128 * 1024;
    const float* Bb = enc + (long long)bz * 1024 * 1024;

    __shared__ __align__(16) unsigned short Ah[128*32];
    __shared__ __align__(16) unsigned short Bt[128*BSTR];

    const int tid = threadIdx.x, lane = tid & 63, wave = tid >> 6;
    const int wm = (wave >> 2) * 64, wn = (wave & 3) * 32;
    const int fr = lane & 15, kq = lane >> 4;
    const int row0 = tid >> 2, c80 = (tid & 3) * 8;
    const int kb = tid & 7, nb2 = tid >> 3;   // 4k x 2n transpose block / thread

    f32x4 zero = {0.f, 0.f, 0.f, 0.f};
    f32x4 acc[4][2];
    #pragma unroll
    for (int i = 0; i < 4; i++)
        #pragma unroll
        for (int j = 0; j < 2; j++) acc[i][j] = zero;

    for (int k0 = 0; k0 < 1024; k0 += 32) {
        const unsigned short* pa = Ab + (long long)row0 * 1024 + k0 + c80;
        g2lds16(pa, &Ah[tid*8]);

        // B: 4x2 fp32 block (rows k, cols n) -> Bt[n][k] bf16 via perm packing
        float2 r0 = *(const float2*)(Bb + (long long)(k0 + kb*4 + 0) * 1024 + n0 + nb2*2);
        float2 r1 = *(const float2*)(Bb + (long long)(k0 + kb*4 + 1) * 1024 + n0 + nb2*2);
        float2 r2 = *(const float2*)(Bb + (long long)(k0 + kb*4 + 2) * 1024 + n0 + nb2*2);
        float2 r3 = *(const float2*)(Bb + (long long)(k0 + kb*4 + 3) * 1024 + n0 + nb2*2);
        uint2 cc;
        cc.x = pkhi(r0.x, r1.x); cc.y = pkhi(r2.x, r3.x);
        *(uint2*)&Bt[(nb2*2 + 0)*BSTR + kb*4] = cc;
        cc.x = pkhi(r0.y, r1.y); cc.y = pkhi(r2.y, r3.y);
        *(uint2*)&Bt[(nb2*2 + 1)*BSTR + kb*4] = cc;
        __syncthreads();

        short8 fa[4], fb[2];
        #pragma unroll
        for (int fi = 0; fi < 4; fi++)
            fa[fi] = *(const short8*)&Ah[(wm + fi*16 + fr)*32 + kq*8];
        #pragma unroll
        for (int fj = 0; fj < 2; fj++)
            fb[fj] = *(const short8*)&Bt[(wn + fj*16 + fr)*BSTR + kq*8];
        #pragma unroll
        for (int fi = 0; fi < 4; fi++)
            #pragma unroll
            for (int fj = 0; fj < 2; fj++)
                acc[fi][fj] = __builtin_amdgcn_mfma_f32_16x16x32_bf16(fa[fi], fb[fj], acc[fi][fj], 0, 0, 0);
        __syncthreads();
    }

    #pragma unroll
    for (int fi = 0; fi < 4; fi++) {
        int rb = bz * 128 + wm + fi*16 + kq*4;
        #pragma unroll
        for (int fj = 0; fj < 2; fj++) {
            int col = n0 + wn + fj*16 + fr;
            #pragma unroll
            for (int j = 0; j < 4; j++)
                ctx[(long long)(rb + j) * 1024 + col] = f2bf(acc[fi][fj][j]);
        }
    }
}

// ---------------------------------------------------------------------------
// out = tanh([ctx|dec] @ W_out^T + b). A pointer switches at k=1024. Pure
// g2lds staging. grid (64,8,1), 512 threads.
// ---------------------------------------------------------------------------
__global__ __launch_bounds__(512, 4) void gemm_out(
    const unsigned short* __restrict__ ctx, const unsigned short* __restrict__ dech,
    const unsigned short* __restrict__ Wb, const float* __restrict__ bias,
    float* __restrict__ out)
{
    const int m0 = blockIdx.x * 128, n0 = blockIdx.y * 128;
    __shared__ __align__(16) unsigned short Ah[128*32], Bh[128*32];

    const int tid = threadIdx.x, lane = tid & 63, wave = tid >> 6;
    const int wm = (wave >> 2) * 64, wn = (wave & 3) * 32;
    const int fr = lane & 15, kq = lane >> 4;
    const int row0 = tid >> 2, c80 = (tid & 3) * 8;

    f32x4 zero = {0.f, 0.f, 0.f, 0.f};
    f32x4 acc[4][2];
    #pragma unroll
    for (int i = 0; i < 4; i++)
        #pragma unroll
        for (int j = 0; j < 2; j++) acc[i][j] = zero;

    for (int k0 = 0; k0 < 2048; k0 += 32) {
        const unsigned short* As = (k0 < 1024) ? ctx : dech;
        int kk = k0 & 1023;
        const unsigned short* pa = As + (long long)(m0 + row0) * 1024 + kk + c80;
        const unsigned short* pb = Wb + (long long)(n0 + row0) * 2048 + k0 + c80;
        g2lds16(pa, &Ah[tid*8]);
        g2lds16(pb, &Bh[tid*8]);
        __syncthreads();

        short8 fa[4], fb[2];
        #pragma unroll
        for (int fi = 0; fi < 4; fi++)
            fa[fi] = *(const short8*)&Ah[(wm + fi*16 + fr)*32 + kq*8];
        #pragma unroll
        for (int fj = 0; fj < 2; fj++)
            fb[fj] = *(const short8*)&Bh[(wn + fj*16 + fr)*32 + kq*8];
        #pragma unroll
        for (int fi = 0; fi < 4; fi++)
            #pragma unroll
            for (int fj = 0; fj < 2; fj++)
                acc[fi][fj] = __builtin_amdgcn_mfma_f32_16x16x32_bf16(fa[fi], fb[fj], acc[fi][fj], 0, 0, 0);
        __syncthreads();
    }

    #pragma unroll
    for (int fi = 0; fi < 4; fi++) {
        int rb = m0 + wm + fi*16 + kq*4;
        #pragma unroll
        for (int fj = 0; fj < 2; fj++) {
            int col = n0 + wn + fj*16 + fr;
            float bb = bias[col];
            #pragma unroll
            for (int j = 0; j < 4; j++)
                out[(long long)(rb + j) * 1024 + col] = tanhf(acc[fi][fj][j] + bb);
        }
    }
}

extern "C" void kernel_launch(void* const* d_in, const int* in_sizes, int n_in,
                              void* d_out, int out_size, void* d_ws, size_t ws_size,
                              hipStream_t stream) {
    const float* dec    = (const float*)d_in[0];   // [64,128,1024]
    const float* enc    = (const float*)d_in[1];   // [64,1024,1024]
    const int*   mask   = (const int*)d_in[2];     // [64,1024]
    const float* W_attn = (const float*)d_in[3];   // [1024,1024]
    const float* W_out  = (const float*)d_in[4];   // [1024,2048]
    const float* b_out  = (const float*)d_in[5];   // [1024]

    float* out_attn = (float*)d_out;               // [8192,1024]
    float* weights  = out_attn + 8388608;          // [8192,1024] scores->softmax in place

    char* ws = (char*)d_ws;
    unsigned short* dec_hi = (unsigned short*)(ws);              // 16 MB
    unsigned short* dec_lo = (unsigned short*)(ws + (16 << 20)); // 16 MB
    unsigned short* wa_hi  = (unsigned short*)(ws + (32 << 20)); //  2 MB
    unsigned short* wa_lo  = (unsigned short*)(ws + (34 << 20)); //  2 MB
    unsigned short* wout_b = (unsigned short*)(ws + (36 << 20)); //  4 MB
    unsigned short* q_hi   = (unsigned short*)(ws + (40 << 20)); // 16 MB
    unsigned short* q_lo   = (unsigned short*)(ws + (56 << 20)); // 16 MB
    unsigned short* w_bf   = (unsigned short*)(ws + (72 << 20)); // 16 MB
    unsigned short* ctx_bf = (unsigned short*)(ws + (88 << 20)); // 16 MB -> 104 MB total

    dim3 blk(256), blk8(512);

    split_rtz<<<dim3(8192), blk, 0, stream>>>(dec, dec_hi, dec_lo);
    split_rtz<<<dim3(1024), blk, 0, stream>>>(W_attn, wa_hi, wa_lo);
    cvt_f32<<<dim3(2048), blk, 0, stream>>>(W_out, wout_b);

    gemm3_qproj<<<dim3(64, 8, 1), blk8, 0, stream>>>(dec_hi, dec_lo, wa_hi, wa_lo, q_hi, q_lo);
    gemm3_scores<<<dim3(1, 8, 64), blk8, 0, stream>>>(q_hi, q_lo, enc, weights);
    softmax_mask<<<dim3(8192), blk, 0, stream>>>(weights, mask, w_bf);
    gemm_ctx<<<dim3(1, 8, 64), blk8, 0, stream>>>(w_bf, enc, ctx_bf);
    gemm_out<<<dim3(64, 8, 1), blk8, 0, stream>>>(ctx_bf, dec_hi, wout_b, b_out, out_attn);
}